// Round 1
// baseline (160.442 us; speedup 1.0000x reference)
//
#include <hip/hip_runtime.h>

// CharGRU2: 2-layer GRU (reset_after=true) + dense + softmax, fp32.
// B=2048, T=128, V=256, H=20, L=15.
// Layout: one batch element per 64-lane wave; lane c (c<60) owns gate-column c
// of the 3H=60-wide gate vectors. h0/h1 live on lanes 0..19 (unit j on lane j).
// Matvecs h@M: broadcast h_k via v_readlane (uniform SGPR) -> v_fmac per lane.
// Gate gathers (columns j+20, j+40) via ds_bpermute with precomputed addrs.

#define BB 2048
#define TT 128
#define HH 20
#define LL 15
#define H3 60

__device__ __forceinline__ float bclane(float v, int k) {
    return __int_as_float(__builtin_amdgcn_readlane(__float_as_int(v), k));
}
__device__ __forceinline__ float bperm(int byteaddr, float v) {
    return __int_as_float(__builtin_amdgcn_ds_bpermute(byteaddr, __float_as_int(v)));
}
__device__ __forceinline__ float fast_rcp(float x) { return __builtin_amdgcn_rcpf(x); }
__device__ __forceinline__ float sigm(float x) { return fast_rcp(1.f + __expf(-x)); }
__device__ __forceinline__ float tanh_f(float x) { return 1.f - 2.f * fast_rcp(1.f + __expf(2.f * x)); }

extern "C" __global__ __launch_bounds__(256)
void gru2_kernel(const int* __restrict__ x, const float* __restrict__ W0,
                 const float* __restrict__ U0, const float* __restrict__ b0i,
                 const float* __restrict__ b0r, const float* __restrict__ W1,
                 const float* __restrict__ U1, const float* __restrict__ b1i,
                 const float* __restrict__ b1r, const float* __restrict__ Wd,
                 const float* __restrict__ bd, float* __restrict__ out)
{
    const int lane = threadIdx.x & 63;
    const int b = blockIdx.x * (blockDim.x >> 6) + (threadIdx.x >> 6); // batch = wave id
    const int c = lane < H3 ? lane : H3 - 1;  // clamp idle lanes 60..63

    // ---- preload weight columns into VGPRs (once per sequence) ----
    float u0c[HH], w1c[HH], u1c[HH];
#pragma unroll
    for (int k = 0; k < HH; ++k) {
        u0c[k] = U0[k * H3 + c];
        w1c[k] = W1[k * H3 + c];
        u1c[k] = U1[k * H3 + c];
    }
    const float b0i_c = b0i[c], b0r_c = b0r[c];
    const float b1i_c = b1i[c], b1r_c = b1r[c];

    // ---- all 128 tokens of this sequence into 2 VGPRs ----
    const int* xrow = x + b * TT;
    const int tokA = xrow[lane];
    const int tokB = xrow[64 + lane];

    // bpermute byte addresses for gate gathers (lane j reads cols j+20, j+40)
    const int a20 = ((lane + 20) & 63) << 2;
    const int a40 = ((lane + 40) & 63) << 2;

    float h0 = 0.f, h1 = 0.f;

    // prefetch xw for t=0
    int tok0 = __builtin_amdgcn_readlane(tokA, 0);
    float xw_cur = W0[tok0 * H3 + c] + b0i_c;

    for (int t = 0; t < TT; ++t) {
        // software-pipeline: issue next step's W0-row gather now
        const int tn = (t + 1 < TT) ? (t + 1) : t;
        const int tokn = __builtin_amdgcn_readlane(tn < 64 ? tokA : tokB, tn & 63);
        const float xw_next = W0[tokn * H3 + c];

        // ---- layer 0: rec0 = h0 @ U0 + b0r (lane c computes column c) ----
        float rec0 = b0r_c;
#pragma unroll
        for (int k = 0; k < HH; ++k)
            rec0 = fmaf(bclane(h0, k), u0c[k], rec0);

        const float xr = bperm(a20, xw_cur), xh = bperm(a40, xw_cur);
        const float rr = bperm(a20, rec0),  rh = bperm(a40, rec0);
        const float z  = sigm(xw_cur + rec0);       // valid on lanes < 20
        const float r  = sigm(xr + rr);
        const float hh = tanh_f(xh + r * rh);
        h0 = fmaf(z, h0 - hh, hh);                  // z*h + (1-z)*hh

        // ---- layer 1: xw1 = h0 @ W1 + b1i ; rec1 = h1 @ U1 + b1r ----
        float xw1 = b1i_c, rec1 = b1r_c;
#pragma unroll
        for (int k = 0; k < HH; ++k) {
            xw1  = fmaf(bclane(h0, k), w1c[k], xw1);
            rec1 = fmaf(bclane(h1, k), u1c[k], rec1);
        }
        const float xr1 = bperm(a20, xw1),  const_xh1 = 0; (void)const_xh1;
        const float xh1 = bperm(a40, xw1);
        const float rr1 = bperm(a20, rec1), rh1 = bperm(a40, rec1);
        const float z1  = sigm(xw1 + rec1);
        const float r1  = sigm(xr1 + rr1);
        const float hh1 = tanh_f(xh1 + r1 * rh1);
        h1 = fmaf(z1, h1 - hh1, hh1);

        xw_cur = xw_next + b0i_c;
    }

    // ---- dense (h1 @ Wd + bd) + softmax, lanes 0..14 ----
    const int l = lane < LL ? lane : LL - 1;
    float acc = bd[l];
#pragma unroll
    for (int k = 0; k < HH; ++k)
        acc = fmaf(bclane(h1, k), Wd[k * LL + l], acc);

    float m = acc;
#pragma unroll
    for (int i = 0; i < LL; ++i) m = fmaxf(m, bclane(acc, i));
    const float e = __expf(acc - m);
    float s = 0.f;
#pragma unroll
    for (int i = 0; i < LL; ++i) s += bclane(e, i);
    const float p = e * fast_rcp(s);

    if (lane < LL) out[b * LL + lane] = p;
}

extern "C" void kernel_launch(void* const* d_in, const int* in_sizes, int n_in,
                              void* d_out, int out_size, void* d_ws, size_t ws_size,
                              hipStream_t stream) {
    const int*   x   = (const int*)  d_in[0];
    const float* W0  = (const float*)d_in[1];
    const float* U0  = (const float*)d_in[2];
    const float* b0i = (const float*)d_in[3];
    const float* b0r = (const float*)d_in[4];
    const float* W1  = (const float*)d_in[5];
    const float* U1  = (const float*)d_in[6];
    const float* b1i = (const float*)d_in[7];
    const float* b1r = (const float*)d_in[8];
    const float* Wd  = (const float*)d_in[9];
    const float* bd  = (const float*)d_in[10];
    // d_in[11] = drop_rate (identity), unused
    float* out = (float*)d_out;

    // 2048 batch elements, 1 per wave, 4 waves per 256-thread block -> 512 blocks
    dim3 grid(BB / 4), block(256);
    hipLaunchKernelGGL(gru2_kernel, grid, block, 0, stream,
                       x, W0, U0, b0i, b0r, W1, U1, b1i, b1r, Wd, bd, out);
}